// Round 3
// baseline (240.657 us; speedup 1.0000x reference)
//
#include <hip/hip_runtime.h>
#include <hip/hip_bf16.h>

#define BB 4
#define CC 256
#define NN 16384

typedef __hip_bfloat16 bf16;
typedef __attribute__((ext_vector_type(8))) short short8;
typedef __attribute__((ext_vector_type(4))) float f32x4;

__device__ __forceinline__ float b2f(unsigned short u) {
  union { unsigned int i; float f; } x; x.i = ((unsigned int)u) << 16; return x.f;
}
__device__ __forceinline__ f32x4 mfma16(short8 a, short8 b, f32x4 c) {
  return __builtin_amdgcn_mfma_f32_16x16x32_bf16(a, b, c, 0, 0, 0);
}
// async global->LDS, 16B per lane; lds dst is wave-uniform base (HW adds lane*16)
__device__ __forceinline__ void gl_lds16(const bf16* g, const bf16* s) {
  __builtin_amdgcn_global_load_lds(
      (const __attribute__((address_space(1))) unsigned int*)(g),
      (__attribute__((address_space(3))) unsigned int*)(s), 16, 0, 0);
}

// ---------------- prep: reorder/convert weights, BN constants, zero KVD ----------------
__global__ __launch_bounds__(256) void prep_kernel(
    const float* __restrict__ Wqkv, const float* __restrict__ Wproj,
    const float* __restrict__ g, const float* __restrict__ bta,
    const float* __restrict__ mu, const float* __restrict__ var,
    bf16* __restrict__ Wq, bf16* __restrict__ Wkv, bf16* __restrict__ Wp,
    float* __restrict__ bns, float* __restrict__ KVD) {
  int i = blockIdx.x * 256 + threadIdx.x;
  if (i < 1024) KVD[i] = 0.f;  // BB*256 accumulators for qkv atomics
  if (i < 768 * 256) {
    int o = i >> 8, c8 = i & 255;
    int c = o / 3, s = o - 3 * c;
    bf16 bv = __float2bfloat16(Wqkv[i]);
    if (s == 0) Wq[c * 256 + c8] = bv;
    else if (s == 1) Wkv[c * 256 + c8] = bv;
    else Wkv[(256 + c) * 256 + c8] = bv;
  }
  int j = i - 768 * 256;
  if (j >= 0 && j < 256 * 256) Wp[j] = __float2bfloat16(Wproj[j]);
  int k = i - (768 * 256 + 256 * 256);
  if (k >= 0 && k < 256) {
    float sc = g[k] * rsqrtf(var[k] + 1e-5f);
    bns[k] = sc;
    bns[256 + k] = bta[k] - mu[k] * sc;
  }
}

// ---------------- K1: x (B,C,N) f32 -> XT (B,N,C) bf16 ----------------
__global__ __launch_bounds__(256) void xt_kernel(const float* __restrict__ X, bf16* __restrict__ XT) {
  __shared__ bf16 tile[64][65];
  int b = blockIdx.z, c0 = blockIdx.y * 64, n0 = blockIdx.x * 64;
  int t = threadIdx.x;
  int nj = t & 63, ci = t >> 6;
  const float* Xb = X + ((size_t)b * CC + c0) * NN + n0;
#pragma unroll
  for (int i = 0; i < 16; ++i)
    tile[ci + 4 * i][nj] = __float2bfloat16(Xb[(size_t)(ci + 4 * i) * NN + nj]);
  __syncthreads();
  bf16* O = XT + ((size_t)b * NN + n0) * CC + c0;
  int cj = t & 63, ni = t >> 6;
#pragma unroll
  for (int i = 0; i < 16; ++i)
    O[(size_t)(ni + 4 * i) * CC + cj] = tile[cj][ni + 4 * i];
}

// ---------------- qkv: 64-n tile; wave w computes q(:,w*64+..), k(w*64+..,:), v(w*64+..,:) ----------------
__global__ __launch_bounds__(256, 4) void qkv_kernel(
    const bf16* __restrict__ XT, const bf16* __restrict__ Wq, const bf16* __restrict__ Wkv,
    bf16* __restrict__ QT, bf16* __restrict__ KB, bf16* __restrict__ VB,
    float* __restrict__ KVD) {
  __shared__ bf16 xs[64 * 256];  // 32 KB, rows 512B, 16B-chunk ^= (row&7)
  int b = blockIdx.y;
  int n0 = blockIdx.x * 64;
  int t = threadIdx.x, w = t >> 6, l = t & 63, lr = l & 15, lk = l >> 4;
  const bf16* base = XT + ((size_t)b * NN + n0) * CC;
#pragma unroll
  for (int i = 0; i < 8; ++i) {
    int row2 = w * 16 + i * 2;             // this inst stages rows row2, row2+1
    int ldsOff = row2 * 512 + l * 16;
    int r = ldsOff >> 9;
    int sc = (ldsOff >> 4) & 31;
    int cc = sc ^ (r & 7);
    gl_lds16(base + (size_t)r * CC + cc * 8, xs + row2 * 256);
  }
  __syncthreads();
  const char* xb = (const char*)xs;

  // ---- unit 1: q[n, w*64+c'] = relu(xs @ Wq^T) ----
  {
    f32x4 acc[4][4] = {};
    for (int k0 = 0; k0 < 256; k0 += 32) {
      short8 a[4];
#pragma unroll
      for (int mt = 0; mt < 4; ++mt) {
        int rn = mt * 16 + lr;
        a[mt] = *(const short8*)(xb + rn * 512 + ((k0 * 2 + lk * 16) ^ ((rn & 7) << 4)));
      }
#pragma unroll
      for (int nt = 0; nt < 4; ++nt) {
        short8 bb = *(const short8*)(Wq + (size_t)(w * 64 + nt * 16 + lr) * CC + k0 + lk * 8);
#pragma unroll
        for (int mt = 0; mt < 4; ++mt) acc[mt][nt] = mfma16(a[mt], bb, acc[mt][nt]);
      }
    }
    bf16* O = QT + ((size_t)b * NN + n0) * CC;
#pragma unroll
    for (int mt = 0; mt < 4; ++mt)
#pragma unroll
      for (int nt = 0; nt < 4; ++nt)
#pragma unroll
        for (int e = 0; e < 4; ++e) {
          int row = mt * 16 + 4 * lk + e;
          int col = w * 64 + nt * 16 + lr;
          float v = acc[mt][nt][e];
          O[(size_t)row * CC + col] = __float2bfloat16(v > 0.f ? v : 0.f);
        }
  }
  // ---- unit 2: k[w*64+c, n] = relu(Wkv @ xs^T); kvd atomics ----
  {
    f32x4 acc[4][4] = {};
    for (int k0 = 0; k0 < 256; k0 += 32) {
      short8 a[4];
#pragma unroll
      for (int mt = 0; mt < 4; ++mt)
        a[mt] = *(const short8*)(Wkv + (size_t)(w * 64 + mt * 16 + lr) * CC + k0 + lk * 8);
#pragma unroll
      for (int nt = 0; nt < 4; ++nt) {
        int rn = nt * 16 + lr;
        short8 bb = *(const short8*)(xb + rn * 512 + ((k0 * 2 + lk * 16) ^ ((rn & 7) << 4)));
#pragma unroll
        for (int mt = 0; mt < 4; ++mt) acc[mt][nt] = mfma16(a[mt], bb, acc[mt][nt]);
      }
    }
    bf16* Out = KB + (size_t)b * CC * NN;
#pragma unroll
    for (int mt = 0; mt < 4; ++mt)
#pragma unroll
      for (int e = 0; e < 4; ++e) {
        float s = 0.f;
#pragma unroll
        for (int nt = 0; nt < 4; ++nt) {
          float v = acc[mt][nt][e];
          v = v > 0.f ? v : 0.f;
          acc[mt][nt][e] = v;
          s += v;
        }
        // reduce over lr (lanes 0-15 of each lk group hold same c, different n)
        s += __shfl_xor(s, 1);
        s += __shfl_xor(s, 2);
        s += __shfl_xor(s, 4);
        s += __shfl_xor(s, 8);
        int c = w * 64 + mt * 16 + 4 * lk + e;
        if (lr == 0) atomicAdd(&KVD[b * 256 + c], s);
      }
#pragma unroll
    for (int mt = 0; mt < 4; ++mt)
#pragma unroll
      for (int nt = 0; nt < 4; ++nt)
#pragma unroll
        for (int e = 0; e < 4; ++e) {
          int c = w * 64 + mt * 16 + 4 * lk + e;
          int n = n0 + nt * 16 + lr;
          Out[(size_t)c * NN + n] = __float2bfloat16(acc[mt][nt][e]);
        }
  }
  // ---- unit 3: v[w*64+c, n] = Wkv[256+..] @ xs^T ----
  {
    f32x4 acc[4][4] = {};
    for (int k0 = 0; k0 < 256; k0 += 32) {
      short8 a[4];
#pragma unroll
      for (int mt = 0; mt < 4; ++mt)
        a[mt] = *(const short8*)(Wkv + (size_t)(256 + w * 64 + mt * 16 + lr) * CC + k0 + lk * 8);
#pragma unroll
      for (int nt = 0; nt < 4; ++nt) {
        int rn = nt * 16 + lr;
        short8 bb = *(const short8*)(xb + rn * 512 + ((k0 * 2 + lk * 16) ^ ((rn & 7) << 4)));
#pragma unroll
        for (int mt = 0; mt < 4; ++mt) acc[mt][nt] = mfma16(a[mt], bb, acc[mt][nt]);
      }
    }
    bf16* Out = VB + (size_t)b * CC * NN;
#pragma unroll
    for (int mt = 0; mt < 4; ++mt)
#pragma unroll
      for (int nt = 0; nt < 4; ++nt)
#pragma unroll
        for (int e = 0; e < 4; ++e) {
          int c = w * 64 + mt * 16 + 4 * lk + e;
          int n = n0 + nt * 16 + lr;
          Out[(size_t)c * NN + n] = __float2bfloat16(acc[mt][nt][e]);
        }
  }
}

// ---------------- G2: PART[c][j] partials = k @ v^T, split-K 16 ----------------
__global__ __launch_bounds__(256) void g2_kernel(const bf16* __restrict__ KB,
                                                 const bf16* __restrict__ VB,
                                                 float* __restrict__ PART) {
  int b = blockIdx.z, chunk = blockIdx.y;
  int tc = (blockIdx.x & 1) * 128;   // c rows (from k)
  int tj = (blockIdx.x >> 1) * 128;  // j cols (from v)
  int nb = chunk * 1024;
  int t = threadIdx.x, w = t >> 6, lane = t & 63, lr = lane & 15, lk = lane >> 4;
  const bf16* A = KB + ((size_t)b * CC + tc + w * 32) * NN + nb;
  const bf16* Bp = VB + ((size_t)b * CC + tj) * NN + nb;
  f32x4 acc[2][8] = {};
  for (int k0 = 0; k0 < 1024; k0 += 32) {
    short8 a[2];
#pragma unroll
    for (int mt = 0; mt < 2; ++mt)
      a[mt] = *(const short8*)(A + (size_t)(mt * 16 + lr) * NN + k0 + lk * 8);
#pragma unroll
    for (int nt = 0; nt < 8; ++nt) {
      short8 bb = *(const short8*)(Bp + (size_t)(nt * 16 + lr) * NN + k0 + lk * 8);
#pragma unroll
      for (int mt = 0; mt < 2; ++mt) acc[mt][nt] = mfma16(a[mt], bb, acc[mt][nt]);
    }
  }
  float* P = PART + (((size_t)(b * 16 + chunk)) << 16);
#pragma unroll
  for (int mt = 0; mt < 2; ++mt)
#pragma unroll
    for (int nt = 0; nt < 8; ++nt)
#pragma unroll
      for (int e = 0; e < 4; ++e) {
        int c = tc + w * 32 + mt * 16 + 4 * lk + e;
        int j = tj + nt * 16 + lr;
        P[(size_t)c * 256 + j] = acc[mt][nt][e];
      }
}

// ---------------- reduce partials -> KVJ bf16 [b][c][j] ----------------
__global__ __launch_bounds__(256) void kvred_kernel(const float* __restrict__ PART, bf16* __restrict__ KVJ) {
  int idx = blockIdx.x * 256 + threadIdx.x;
  int b = idx >> 16, rem = idx & 65535;
  float s = 0.f;
#pragma unroll
  for (int ch = 0; ch < 16; ++ch) s += PART[(((size_t)(b * 16 + ch)) << 16) + rem];
  KVJ[idx] = __float2bfloat16(s);
}

// ---------------- mker: M[o][c] = scale[o] * sum_j Wp[o,j] * KVJ[c,j] ----------------
__global__ __launch_bounds__(256) void mker_kernel(const bf16* __restrict__ Wp,
                                                   const bf16* __restrict__ KVJ,
                                                   const float* __restrict__ bns,
                                                   bf16* __restrict__ Mb) {
  int b = blockIdx.z;
  int o0 = blockIdx.x * 128, c0 = blockIdx.y * 128;
  int t = threadIdx.x, w = t >> 6, lane = t & 63, lr = lane & 15, lk = lane >> 4;
  const bf16* A = Wp + (size_t)(o0 + w * 32) * 256;
  const bf16* Bp = KVJ + ((size_t)b << 16) + (size_t)c0 * 256;
  f32x4 acc[2][8] = {};
  for (int k0 = 0; k0 < 256; k0 += 32) {
    short8 a[2];
#pragma unroll
    for (int mt = 0; mt < 2; ++mt)
      a[mt] = *(const short8*)(A + (size_t)(mt * 16 + lr) * 256 + k0 + lk * 8);
#pragma unroll
    for (int nt = 0; nt < 8; ++nt) {
      short8 bb = *(const short8*)(Bp + (size_t)(nt * 16 + lr) * 256 + k0 + lk * 8);
#pragma unroll
      for (int mt = 0; mt < 2; ++mt) acc[mt][nt] = mfma16(a[mt], bb, acc[mt][nt]);
    }
  }
#pragma unroll
  for (int mt = 0; mt < 2; ++mt)
#pragma unroll
    for (int nt = 0; nt < 8; ++nt)
#pragma unroll
      for (int e = 0; e < 4; ++e) {
        int o = o0 + w * 32 + mt * 16 + 4 * lk + e;
        int c = c0 + nt * 16 + lr;
        Mb[((size_t)b << 16) + (size_t)o * 256 + c] = __float2bfloat16(acc[mt][nt][e] * bns[o]);
      }
}

// ---------------- g5: y[o,n] = (sum_c M[o,c] q[n,c]) * recip[n] + shift[o] ----------------
__global__ __launch_bounds__(256, 4) void g5_kernel(const bf16* __restrict__ QT,
                                                    const bf16* __restrict__ Mb,
                                                    const float* __restrict__ KVD,
                                                    const float* __restrict__ bns,
                                                    float* __restrict__ Y) {
  __shared__ bf16 qs[64 * 256];  // 32 KB swizzled
  __shared__ float recip_s[64];
  __shared__ float shs[256];
  int b = blockIdx.y;
  int n0 = blockIdx.x * 64;
  int t = threadIdx.x, w = t >> 6, l = t & 63, lr = l & 15, lk = l >> 4;
  shs[t] = bns[256 + t];
  const bf16* qbase = QT + ((size_t)b * NN + n0) * CC;
#pragma unroll
  for (int i = 0; i < 8; ++i) {
    int row2 = w * 16 + i * 2;
    int ldsOff = row2 * 512 + l * 16;
    int r = ldsOff >> 9;
    int sc = (ldsOff >> 4) & 31;
    int cc = sc ^ (r & 7);
    gl_lds16(qbase + (size_t)r * CC + cc * 8, qs + row2 * 256);
  }
  __syncthreads();
  const char* qb = (const char*)qs;
  // denominator: 4 threads per n-row, each covers a 64-c quarter
  {
    int row = t >> 2, qtr = t & 3;
    const float* kd = KVD + b * 256 + qtr * 64;
    float s = 0.f;
#pragma unroll
    for (int j = 0; j < 8; ++j) {
      int chunk = qtr * 8 + j;
      short8 v = *(const short8*)(qb + row * 512 + ((chunk * 16) ^ ((row & 7) << 4)));
#pragma unroll
      for (int e = 0; e < 8; ++e) s += b2f((unsigned short)v[e]) * kd[j * 8 + e];
    }
    s += __shfl_xor(s, 1);
    s += __shfl_xor(s, 2);
    if (qtr == 0) recip_s[row] = 1.f / (s + 1e-5f);
  }
  __syncthreads();
  // GEMM: wave w handles o rows w*64..w*64+63, all 64 n
  const bf16* Ab = Mb + ((size_t)b << 16) + (size_t)(w * 64) * 256;
  f32x4 acc[4][4] = {};
  for (int k0 = 0; k0 < 256; k0 += 32) {
    short8 a[4];
#pragma unroll
    for (int mt = 0; mt < 4; ++mt)
      a[mt] = *(const short8*)(Ab + (size_t)(mt * 16 + lr) * 256 + k0 + lk * 8);
#pragma unroll
    for (int nt = 0; nt < 4; ++nt) {
      int rn = nt * 16 + lr;
      short8 bb = *(const short8*)(qb + rn * 512 + ((k0 * 2 + lk * 16) ^ ((rn & 7) << 4)));
#pragma unroll
      for (int mt = 0; mt < 4; ++mt) acc[mt][nt] = mfma16(a[mt], bb, acc[mt][nt]);
    }
  }
  float* Yb = Y + (size_t)b * CC * NN;
#pragma unroll
  for (int mt = 0; mt < 4; ++mt)
#pragma unroll
    for (int nt = 0; nt < 4; ++nt)
#pragma unroll
      for (int e = 0; e < 4; ++e) {
        int o = w * 64 + mt * 16 + 4 * lk + e;
        int n = nt * 16 + lr;
        Yb[(size_t)o * NN + n0 + n] = acc[mt][nt][e] * recip_s[n] + shs[o];
      }
}

extern "C" void kernel_launch(void* const* d_in, const int* in_sizes, int n_in,
                              void* d_out, int out_size, void* d_ws, size_t ws_size,
                              hipStream_t stream) {
  const float* x = (const float*)d_in[0];
  const float* Wqkv = (const float*)d_in[1];
  const float* Wproj = (const float*)d_in[2];
  const float* g = (const float*)d_in[3];
  const float* bta = (const float*)d_in[4];
  const float* mu = (const float*)d_in[5];
  const float* var = (const float*)d_in[6];
  float* Y = (float*)d_out;

  char* ws = (char*)d_ws;
  size_t off = 0;
  auto alloc = [&](size_t bytes) -> void* {
    void* p = ws + off;
    off += (bytes + 255) & ~(size_t)255;
    return p;
  };
  const size_t big = (size_t)BB * NN * CC * 2;  // 33.5 MB
  bf16* XT = (bf16*)alloc(big);
  float* PART = (float*)XT;  // overlay: XT dead before g2 writes PART
  bf16* QT = (bf16*)alloc(big);
  bf16* KB = (bf16*)alloc(big);
  bf16* VB = (bf16*)alloc(big);
  bf16* KVJ = (bf16*)alloc((size_t)BB * 256 * 256 * 2);
  bf16* Mbuf = (bf16*)alloc((size_t)BB * 256 * 256 * 2);
  float* KVD = (float*)alloc((size_t)BB * 256 * 4);
  bf16* Wq = (bf16*)alloc(256 * 256 * 2);
  bf16* Wkv = (bf16*)alloc(512 * 256 * 2);
  bf16* Wp = (bf16*)alloc(256 * 256 * 2);
  float* bns = (float*)alloc(512 * 4);

  prep_kernel<<<1025, 256, 0, stream>>>(Wqkv, Wproj, g, bta, mu, var, Wq, Wkv, Wp, bns, KVD);
  xt_kernel<<<dim3(NN / 64, CC / 64, BB), 256, 0, stream>>>(x, XT);
  qkv_kernel<<<dim3(NN / 64, BB), 256, 0, stream>>>(XT, Wq, Wkv, QT, KB, VB, KVD);
  g2_kernel<<<dim3(4, 16, BB), 256, 0, stream>>>(KB, VB, PART);
  kvred_kernel<<<BB * 256 * 256 / 256, 256, 0, stream>>>(PART, KVJ);
  mker_kernel<<<dim3(2, 2, BB), 256, 0, stream>>>(Wp, KVJ, bns, Mbuf);
  g5_kernel<<<dim3(NN / 64, BB), 256, 0, stream>>>(QT, Mbuf, KVD, bns, Y);
}

// Round 4
// 176.753 us; speedup vs baseline: 1.3615x; 1.3615x over previous
//
#include <hip/hip_runtime.h>
#include <hip/hip_bf16.h>

#define BB 4
#define CC 256
#define NN 16384

typedef __hip_bfloat16 bf16;
typedef __attribute__((ext_vector_type(8))) short short8;
typedef __attribute__((ext_vector_type(4))) float f32x4;

__device__ __forceinline__ float b2f(unsigned short u) {
  union { unsigned int i; float f; } x; x.i = ((unsigned int)u) << 16; return x.f;
}
__device__ __forceinline__ f32x4 mfma16(short8 a, short8 b, f32x4 c) {
  return __builtin_amdgcn_mfma_f32_16x16x32_bf16(a, b, c, 0, 0, 0);
}
// async global->LDS, 16B per lane; lds dst is wave-uniform base (HW adds lane*16)
__device__ __forceinline__ void gl_lds16(const bf16* g, const bf16* s) {
  __builtin_amdgcn_global_load_lds(
      (const __attribute__((address_space(1))) unsigned int*)(g),
      (__attribute__((address_space(3))) unsigned int*)(s), 16, 0, 0);
}

// ---------------- prep: reorder/convert weights, BN constants, zero KVD ----------------
__global__ __launch_bounds__(256) void prep_kernel(
    const float* __restrict__ Wqkv, const float* __restrict__ Wproj,
    const float* __restrict__ g, const float* __restrict__ bta,
    const float* __restrict__ mu, const float* __restrict__ var,
    bf16* __restrict__ Wq, bf16* __restrict__ Wkv, bf16* __restrict__ Wp,
    float* __restrict__ bns, float* __restrict__ KVD) {
  int i = blockIdx.x * 256 + threadIdx.x;
  if (i < 1024) KVD[i] = 0.f;  // BB*256 accumulators for qkv atomics
  if (i < 768 * 256) {
    int o = i >> 8, c8 = i & 255;
    int c = o / 3, s = o - 3 * c;
    bf16 bv = __float2bfloat16(Wqkv[i]);
    if (s == 0) Wq[c * 256 + c8] = bv;
    else if (s == 1) Wkv[c * 256 + c8] = bv;
    else Wkv[(256 + c) * 256 + c8] = bv;
  }
  int j = i - 768 * 256;
  if (j >= 0 && j < 256 * 256) Wp[j] = __float2bfloat16(Wproj[j]);
  int k = i - (768 * 256 + 256 * 256);
  if (k >= 0 && k < 256) {
    float sc = g[k] * rsqrtf(var[k] + 1e-5f);
    bns[k] = sc;
    bns[256 + k] = bta[k] - mu[k] * sc;
  }
}

// ---------------- K1: x (B,C,N) f32 -> XT (B,N,C) bf16 ----------------
__global__ __launch_bounds__(256) void xt_kernel(const float* __restrict__ X, bf16* __restrict__ XT) {
  __shared__ bf16 tile[64][65];
  int b = blockIdx.z, c0 = blockIdx.y * 64, n0 = blockIdx.x * 64;
  int t = threadIdx.x;
  int nj = t & 63, ci = t >> 6;
  const float* Xb = X + ((size_t)b * CC + c0) * NN + n0;
#pragma unroll
  for (int i = 0; i < 16; ++i)
    tile[ci + 4 * i][nj] = __float2bfloat16(Xb[(size_t)(ci + 4 * i) * NN + nj]);
  __syncthreads();
  bf16* O = XT + ((size_t)b * NN + n0) * CC + c0;
  int cj = t & 63, ni = t >> 6;
#pragma unroll
  for (int i = 0; i < 16; ++i)
    O[(size_t)(ni + 4 * i) * CC + cj] = tile[cj][ni + 4 * i];
}

// ---------------- qkv: 128-n tile; reg-persistent Wq slice; kvd folded ----------------
__global__ __launch_bounds__(256, 2) void qkv_kernel(
    const bf16* __restrict__ XT, const bf16* __restrict__ Wq, const bf16* __restrict__ Wkv,
    bf16* __restrict__ QT, bf16* __restrict__ KB, bf16* __restrict__ VB,
    float* __restrict__ KVD) {
  __shared__ bf16 xs[128 * 256];  // 64 KB, rows 512B, 16B-chunk ^= (row&7)
  int b = blockIdx.y;
  int n0 = blockIdx.x * 128;
  int t = threadIdx.x, w = t >> 6, l = t & 63, lr = l & 15, lk = l >> 4;
  const bf16* base = XT + ((size_t)b * NN + n0) * CC;
#pragma unroll
  for (int i = 0; i < 16; ++i) {
    int row2 = w * 32 + i * 2;  // stages rows row2, row2+1
    int ldsOff = row2 * 512 + l * 16;
    int r = ldsOff >> 9;
    int sc = (ldsOff >> 4) & 31;
    int cc = sc ^ (r & 7);
    gl_lds16(base + (size_t)r * CC + cc * 8, xs + row2 * 256);
  }
  // preload this wave's Wq c-slice fragments (latency hides under gl_lds)
  short8 wfrag[8][4];
#pragma unroll
  for (int k0i = 0; k0i < 8; ++k0i)
#pragma unroll
    for (int nt = 0; nt < 4; ++nt)
      wfrag[k0i][nt] = *(const short8*)(Wq + (size_t)(w * 64 + nt * 16 + lr) * CC + k0i * 32 + lk * 8);
  __syncthreads();
  const char* xb = (const char*)xs;

  // ---- phase q: q[n, w*64+c'] = relu(xs @ Wq_slice^T); two 64-n passes ----
  {
    bf16* O = QT + ((size_t)b * NN + n0) * CC;
#pragma unroll
    for (int p = 0; p < 2; ++p) {
      f32x4 acc[4][4] = {};
#pragma unroll
      for (int k0i = 0; k0i < 8; ++k0i) {
        short8 a[4];
#pragma unroll
        for (int mt = 0; mt < 4; ++mt) {
          int rn = p * 64 + mt * 16 + lr;
          a[mt] = *(const short8*)(xb + rn * 512 + ((k0i * 64 + lk * 16) ^ ((rn & 7) << 4)));
        }
#pragma unroll
        for (int nt = 0; nt < 4; ++nt)
#pragma unroll
          for (int mt = 0; mt < 4; ++mt) acc[mt][nt] = mfma16(a[mt], wfrag[k0i][nt], acc[mt][nt]);
      }
#pragma unroll
      for (int mt = 0; mt < 4; ++mt)
#pragma unroll
        for (int nt = 0; nt < 4; ++nt)
#pragma unroll
          for (int e = 0; e < 4; ++e) {
            int row = p * 64 + mt * 16 + 4 * lk + e;
            int col = w * 64 + nt * 16 + lr;
            float v = acc[mt][nt][e];
            O[(size_t)row * CC + col] = __float2bfloat16(v > 0.f ? v : 0.f);
          }
    }
  }
  // ---- phase k: k[w*64+c, n] = relu(Wkv_slice @ xs^T); kvd atomics ----
  {
    f32x4 acc[4][8] = {};
    for (int k0 = 0; k0 < 256; k0 += 32) {
      short8 a[4];
#pragma unroll
      for (int mt = 0; mt < 4; ++mt)
        a[mt] = *(const short8*)(Wkv + (size_t)(w * 64 + mt * 16 + lr) * CC + k0 + lk * 8);
#pragma unroll
      for (int nt = 0; nt < 8; ++nt) {
        int rn = nt * 16 + lr;
        short8 bb = *(const short8*)(xb + rn * 512 + ((k0 * 2 + lk * 16) ^ ((rn & 7) << 4)));
#pragma unroll
        for (int mt = 0; mt < 4; ++mt) acc[mt][nt] = mfma16(a[mt], bb, acc[mt][nt]);
      }
    }
    bf16* Out = KB + (size_t)b * CC * NN;
#pragma unroll
    for (int mt = 0; mt < 4; ++mt)
#pragma unroll
      for (int e = 0; e < 4; ++e) {
        float s = 0.f;
#pragma unroll
        for (int nt = 0; nt < 8; ++nt) {
          float v = acc[mt][nt][e];
          v = v > 0.f ? v : 0.f;
          acc[mt][nt][e] = v;
          s += v;
        }
        // lanes sharing (c): reduce across lr (covers all 128 n with nt loop)
        s += __shfl_xor(s, 1);
        s += __shfl_xor(s, 2);
        s += __shfl_xor(s, 4);
        s += __shfl_xor(s, 8);
        int c = w * 64 + mt * 16 + 4 * lk + e;
        if (lr == 0) atomicAdd(&KVD[b * 256 + c], s);
      }
#pragma unroll
    for (int mt = 0; mt < 4; ++mt)
#pragma unroll
      for (int nt = 0; nt < 8; ++nt)
#pragma unroll
        for (int e = 0; e < 4; ++e) {
          int c = w * 64 + mt * 16 + 4 * lk + e;
          int n = n0 + nt * 16 + lr;
          Out[(size_t)c * NN + n] = __float2bfloat16(acc[mt][nt][e]);
        }
  }
  // ---- phase v: v[w*64+c, n] = Wkv[256+slice] @ xs^T ----
  {
    f32x4 acc[4][8] = {};
    for (int k0 = 0; k0 < 256; k0 += 32) {
      short8 a[4];
#pragma unroll
      for (int mt = 0; mt < 4; ++mt)
        a[mt] = *(const short8*)(Wkv + (size_t)(256 + w * 64 + mt * 16 + lr) * CC + k0 + lk * 8);
#pragma unroll
      for (int nt = 0; nt < 8; ++nt) {
        int rn = nt * 16 + lr;
        short8 bb = *(const short8*)(xb + rn * 512 + ((k0 * 2 + lk * 16) ^ ((rn & 7) << 4)));
#pragma unroll
        for (int mt = 0; mt < 4; ++mt) acc[mt][nt] = mfma16(a[mt], bb, acc[mt][nt]);
      }
    }
    bf16* Out = VB + (size_t)b * CC * NN;
#pragma unroll
    for (int mt = 0; mt < 4; ++mt)
#pragma unroll
      for (int nt = 0; nt < 8; ++nt)
#pragma unroll
        for (int e = 0; e < 4; ++e) {
          int c = w * 64 + mt * 16 + 4 * lk + e;
          int n = n0 + nt * 16 + lr;
          Out[(size_t)c * NN + n] = __float2bfloat16(acc[mt][nt][e]);
        }
  }
}

// ---------------- G2: PART[c][j] partials = k @ v^T, split-K 16 ----------------
__global__ __launch_bounds__(256) void g2_kernel(const bf16* __restrict__ KB,
                                                 const bf16* __restrict__ VB,
                                                 float* __restrict__ PART) {
  int b = blockIdx.z, chunk = blockIdx.y;
  int tc = (blockIdx.x & 1) * 128;   // c rows (from k)
  int tj = (blockIdx.x >> 1) * 128;  // j cols (from v)
  int nb = chunk * 1024;
  int t = threadIdx.x, w = t >> 6, lane = t & 63, lr = lane & 15, lk = lane >> 4;
  const bf16* A = KB + ((size_t)b * CC + tc + w * 32) * NN + nb;
  const bf16* Bp = VB + ((size_t)b * CC + tj) * NN + nb;
  f32x4 acc[2][8] = {};
  for (int k0 = 0; k0 < 1024; k0 += 32) {
    short8 a[2];
#pragma unroll
    for (int mt = 0; mt < 2; ++mt)
      a[mt] = *(const short8*)(A + (size_t)(mt * 16 + lr) * NN + k0 + lk * 8);
#pragma unroll
    for (int nt = 0; nt < 8; ++nt) {
      short8 bb = *(const short8*)(Bp + (size_t)(nt * 16 + lr) * NN + k0 + lk * 8);
#pragma unroll
      for (int mt = 0; mt < 2; ++mt) acc[mt][nt] = mfma16(a[mt], bb, acc[mt][nt]);
    }
  }
  float* P = PART + (((size_t)(b * 16 + chunk)) << 16);
#pragma unroll
  for (int mt = 0; mt < 2; ++mt)
#pragma unroll
    for (int nt = 0; nt < 8; ++nt)
#pragma unroll
      for (int e = 0; e < 4; ++e) {
        int c = tc + w * 32 + mt * 16 + 4 * lk + e;
        int j = tj + nt * 16 + lr;
        P[(size_t)c * 256 + j] = acc[mt][nt][e];
      }
}

// ---------------- reduce partials -> KVJ bf16 [b][c][j] ----------------
__global__ __launch_bounds__(256) void kvred_kernel(const float* __restrict__ PART, bf16* __restrict__ KVJ) {
  int idx = blockIdx.x * 256 + threadIdx.x;
  int b = idx >> 16, rem = idx & 65535;
  float s = 0.f;
#pragma unroll
  for (int ch = 0; ch < 16; ++ch) s += PART[(((size_t)(b * 16 + ch)) << 16) + rem];
  KVJ[idx] = __float2bfloat16(s);
}

// ---------------- mker: M[o][c] = scale[o] * sum_j Wp[o,j] * KVJ[c,j] ----------------
__global__ __launch_bounds__(256) void mker_kernel(const bf16* __restrict__ Wp,
                                                   const bf16* __restrict__ KVJ,
                                                   const float* __restrict__ bns,
                                                   bf16* __restrict__ Mb) {
  int b = blockIdx.z;
  int o0 = blockIdx.x * 128, c0 = blockIdx.y * 128;
  int t = threadIdx.x, w = t >> 6, lane = t & 63, lr = lane & 15, lk = lane >> 4;
  const bf16* A = Wp + (size_t)(o0 + w * 32) * 256;
  const bf16* Bp = KVJ + ((size_t)b << 16) + (size_t)c0 * 256;
  f32x4 acc[2][8] = {};
  for (int k0 = 0; k0 < 256; k0 += 32) {
    short8 a[2];
#pragma unroll
    for (int mt = 0; mt < 2; ++mt)
      a[mt] = *(const short8*)(A + (size_t)(mt * 16 + lr) * 256 + k0 + lk * 8);
#pragma unroll
    for (int nt = 0; nt < 8; ++nt) {
      short8 bb = *(const short8*)(Bp + (size_t)(nt * 16 + lr) * 256 + k0 + lk * 8);
#pragma unroll
      for (int mt = 0; mt < 2; ++mt) acc[mt][nt] = mfma16(a[mt], bb, acc[mt][nt]);
    }
  }
#pragma unroll
  for (int mt = 0; mt < 2; ++mt)
#pragma unroll
    for (int nt = 0; nt < 8; ++nt)
#pragma unroll
      for (int e = 0; e < 4; ++e) {
        int o = o0 + w * 32 + mt * 16 + 4 * lk + e;
        int c = c0 + nt * 16 + lr;
        Mb[((size_t)b << 16) + (size_t)o * 256 + c] = __float2bfloat16(acc[mt][nt][e] * bns[o]);
      }
}

// ---------------- g5: y[o,n] = (sum_c M[o,c] q[n,c]) * recip[n] + shift[o] ----------------
__global__ __launch_bounds__(256, 2) void g5_kernel(const bf16* __restrict__ QT,
                                                    const bf16* __restrict__ Mb,
                                                    const float* __restrict__ KVD,
                                                    const float* __restrict__ bns,
                                                    float* __restrict__ Y) {
  __shared__ bf16 qs[128 * 128];   // 32 KB, rows 256B, chunk ^= (row&7)
  __shared__ float recip_s[128];
  __shared__ float shift_s[256];
  int b = blockIdx.y;
  int n0 = blockIdx.x * 128;
  int t = threadIdx.x, w = t >> 6, l = t & 63, lr = l & 15, lk = l >> 4;
  shift_s[t] = bns[256 + t];
  const bf16* qbase = QT + ((size_t)b * NN + n0) * CC;
  const bf16* Ab = Mb + ((size_t)b << 16) + (size_t)(w * 64) * 256;
  const float* kd = KVD + b * 256;
  const char* qb = (const char*)qs;
  float den = 0.f;
  f32x4 acc[4][8] = {};
#pragma unroll
  for (int h = 0; h < 2; ++h) {
    if (h) __syncthreads();
#pragma unroll
    for (int i = 0; i < 8; ++i) {
      int ldsOff = (w * 8 + i) * 1024 + l * 16;
      int r = ldsOff >> 8;
      int sc = (ldsOff >> 4) & 15;
      int cc = sc ^ (r & 7);
      gl_lds16(qbase + (size_t)r * CC + h * 128 + cc * 8, qs + ((w * 8 + i) * 512));
    }
    __syncthreads();
    // denominator partial from staged tile
    {
      int row = t >> 1, seg = t & 1;
      float s = 0.f;
#pragma unroll
      for (int jj = 0; jj < 8; ++jj) {
        int chunk = seg * 8 + jj;
        short8 v = *(const short8*)(qb + row * 256 + ((chunk * 16) ^ ((row & 7) << 4)));
        const float* kp = kd + h * 128 + chunk * 8;
#pragma unroll
        for (int e = 0; e < 8; ++e) s += b2f((unsigned short)v[e]) * kp[e];
      }
      den += s;
    }
    // GEMM over this K-half
    for (int kk = 0; kk < 128; kk += 32) {
      short8 a[4];
#pragma unroll
      for (int mt = 0; mt < 4; ++mt)
        a[mt] = *(const short8*)(Ab + (size_t)(mt * 16 + lr) * 256 + h * 128 + kk + lk * 8);
#pragma unroll
      for (int nt = 0; nt < 8; ++nt) {
        int rn = nt * 16 + lr;
        short8 bb = *(const short8*)(qb + rn * 256 + ((kk * 2 + lk * 16) ^ ((rn & 7) << 4)));
#pragma unroll
        for (int mt = 0; mt < 4; ++mt) acc[mt][nt] = mfma16(a[mt], bb, acc[mt][nt]);
      }
    }
  }
  den += __shfl_xor(den, 1);
  if ((t & 1) == 0) recip_s[t >> 1] = 1.f / (den + 1e-5f);
  __syncthreads();
  float* Yb = Y + (size_t)b * CC * NN;
#pragma unroll
  for (int mt = 0; mt < 4; ++mt)
#pragma unroll
    for (int nt = 0; nt < 8; ++nt)
#pragma unroll
      for (int e = 0; e < 4; ++e) {
        int o = w * 64 + mt * 16 + 4 * lk + e;
        int n = nt * 16 + lr;
        Yb[(size_t)o * NN + n0 + n] = acc[mt][nt][e] * recip_s[n] + shift_s[o];
      }
}

extern "C" void kernel_launch(void* const* d_in, const int* in_sizes, int n_in,
                              void* d_out, int out_size, void* d_ws, size_t ws_size,
                              hipStream_t stream) {
  const float* x = (const float*)d_in[0];
  const float* Wqkv = (const float*)d_in[1];
  const float* Wproj = (const float*)d_in[2];
  const float* g = (const float*)d_in[3];
  const float* bta = (const float*)d_in[4];
  const float* mu = (const float*)d_in[5];
  const float* var = (const float*)d_in[6];
  float* Y = (float*)d_out;

  char* ws = (char*)d_ws;
  size_t off = 0;
  auto alloc = [&](size_t bytes) -> void* {
    void* p = ws + off;
    off += (bytes + 255) & ~(size_t)255;
    return p;
  };
  const size_t big = (size_t)BB * NN * CC * 2;  // 33.5 MB
  bf16* XT = (bf16*)alloc(big);
  float* PART = (float*)XT;  // overlay: XT dead before g2 writes PART
  bf16* QT = (bf16*)alloc(big);
  bf16* KB = (bf16*)alloc(big);
  bf16* VB = (bf16*)alloc(big);
  bf16* KVJ = (bf16*)alloc((size_t)BB * 256 * 256 * 2);
  bf16* Mbuf = (bf16*)alloc((size_t)BB * 256 * 256 * 2);
  float* KVD = (float*)alloc((size_t)BB * 256 * 4);
  bf16* Wq = (bf16*)alloc(256 * 256 * 2);
  bf16* Wkv = (bf16*)alloc(512 * 256 * 2);
  bf16* Wp = (bf16*)alloc(256 * 256 * 2);
  float* bns = (float*)alloc(512 * 4);

  prep_kernel<<<1025, 256, 0, stream>>>(Wqkv, Wproj, g, bta, mu, var, Wq, Wkv, Wp, bns, KVD);
  xt_kernel<<<dim3(NN / 64, CC / 64, BB), 256, 0, stream>>>(x, XT);
  qkv_kernel<<<dim3(NN / 128, BB), 256, 0, stream>>>(XT, Wq, Wkv, QT, KB, VB, KVD);
  g2_kernel<<<dim3(4, 16, BB), 256, 0, stream>>>(KB, VB, PART);
  kvred_kernel<<<BB * 256 * 256 / 256, 256, 0, stream>>>(PART, KVJ);
  mker_kernel<<<dim3(2, 2, BB), 256, 0, stream>>>(Wp, KVJ, bns, Mbuf);
  g5_kernel<<<dim3(NN / 128, BB), 256, 0, stream>>>(QT, Mbuf, KVD, bns, Y);
}